// Round 9
// baseline (748.071 us; speedup 1.0000x reference)
//
#include <hip/hip_runtime.h>

// SpatialStyleModLayer fused kernel, round 9 (MI355X / gfx950)
//   mod  = style @ affine_w^T + affine_b + 1
//   out0 = (x * mod) @ W ;  ssq = (mod^2) @ (W^2) ;  out = out0*rsqrt(ssq+eps)+bias
// R9: 2 persistent blocks/CU (16 waves/CU) + register cross-tile prefetch.
//   R4: 16 waves, no prefetch -> 284us. R8: prefetch, 8 waves -> 353us.
//   R5: prefetch at acc=64 -> spill. Fix: BM=32 with 512 thr -> acc=32,
//   prefetch sld+xld = 32 regs, peak ~100 < 128 (launch_bounds(512,4)).
//   LDS 32KB/block (A_s 16K + B_s 16K; epilogue overlays both as f32 stage).
//   grid = 512 persistent blocks x NT=16 tiles x BM=32 rows.

#define CH   256
#define BM   32
#define NT   16
#define EPS  1e-8f

typedef __attribute__((ext_vector_type(4))) float f32x4;
typedef __attribute__((ext_vector_type(8))) short bf16x8;
typedef __attribute__((ext_vector_type(4))) short s16x4;

__device__ __forceinline__ short f2b(float f) {          // f32 -> bf16 RNE (HW cvt)
    __bf16 h = (__bf16)f;
    return __builtin_bit_cast(short, h);
}
__device__ __forceinline__ float b2f(short b) {
    union { unsigned u; float f; } v;
    v.u = ((unsigned)(unsigned short)b) << 16;
    return v.f;
}
// Swizzled byte offset into a 32-row x 512B-row bf16 tile. chunk = 16B unit (0..31).
__device__ __forceinline__ int swz(int row, int chunk) {
    return row * 512 + ((chunk ^ (row & 7)) << 4);
}

// One-time weight prep: wTb[o][i]=bf16(W[i][o]); wT2b[o][i]=bf16(bf16(W)^2);
// affwb[i][s]=bf16(affw[i][s]).
__global__ void prep_kernel(const float* __restrict__ weight,
                            const float* __restrict__ affw,
                            short* __restrict__ wTb, short* __restrict__ wT2b,
                            short* __restrict__ affwb)
{
    int t = threadIdx.x, b = blockIdx.x;
    float w  = weight[t * CH + b];
    short wb = f2b(w);
    float wf = b2f(wb);
    wTb  [b * CH + t] = wb;
    wT2b [b * CH + t] = f2b(wf * wf);
    affwb[b * CH + t] = f2b(affw[b * CH + t]);
}

__global__ __launch_bounds__(512, 4)
void smod_main(const float* __restrict__ x, const float* __restrict__ style,
               const float* __restrict__ bias, const float* __restrict__ affb,
               const short* __restrict__ wTb, const short* __restrict__ wT2b,
               const short* __restrict__ affwb,
               float* __restrict__ out)
{
    __shared__ __align__(16) unsigned char smem[32768];  // exactly 32 KB
    char*  A_s = (char*)smem;                  // 16 KB: style-bf16 -> a1 (swizzled)
    char*  B_s = (char*)smem + 16384;          // 16 KB: mod -> a2 (swizzled)
    float* st  = (float*)smem;                 // epilogue stage [32][256] f32 (overlay)

    const int tid  = threadIdx.x;
    const int lane = tid & 63;
    const int wid  = tid >> 6;                 // 0..7
    const int l15  = lane & 15;
    const int lgrp = lane >> 4;                // 0..3
    const int koff = lgrp << 3;
    const long rblk = (long)blockIdx.x * (BM * NT);

    // staging unit mapping: u = k*512 + tid -> row = u>>5 (0..31), ch = u&31
    const int urow0 = tid >> 5;                // k=0 row
    const int uch   = tid & 31;

    // cross-tile prefetch registers (16 VGPR each generation)
    f32x4 sld[2][2], xld[2][2];
    {   // prologue: tile 0 style + x
        #pragma unroll
        for (int k = 0; k < 2; ++k) {
            int row = (k << 4) + urow0;
            const float* p = style + (rblk + row) * CH + uch * 8;
            sld[k][0] = *(const f32x4*)p;  sld[k][1] = *(const f32x4*)(p + 4);
        }
        #pragma unroll
        for (int k = 0; k < 2; ++k) {
            int row = (k << 4) + urow0;
            const float* p = x + (rblk + row) * CH + uch * 8;
            xld[k][0] = *(const f32x4*)p;  xld[k][1] = *(const f32x4*)(p + 4);
        }
    }

    #pragma unroll 1
    for (int t = 0; t < NT; ++t) {
        const long r0 = rblk + (long)t * BM;
        __syncthreads();                                 // BAR0: prev stores done, LDS free

        // ---- cvt style(t) regs -> A_s (swizzled b128 writes); refill sld(t+1) ----
        #pragma unroll
        for (int k = 0; k < 2; ++k) {
            int row = (k << 4) + urow0;
            bf16x8 v;
            #pragma unroll
            for (int j = 0; j < 8; ++j)
                v[j] = f2b(j < 4 ? sld[k][0][j] : sld[k][1][j - 4]);
            *(bf16x8*)(A_s + swz(row, uch)) = v;
        }
        if (t + 1 < NT) {
            const float* sp = style + (r0 + BM) * CH;
            #pragma unroll
            for (int k = 0; k < 2; ++k) {
                int row = (k << 4) + urow0;
                const float* p = sp + row * CH + uch * 8;
                sld[k][0] = *(const f32x4*)p;  sld[k][1] = *(const f32x4*)(p + 4);
            }
        }
        __syncthreads();                                 // BAR1: A_s (style) visible

        // ---- Phase 1: mod^T = affwb @ style^T (wave owns 32 i's) ----
        f32x4 accm[2][2];
        #pragma unroll
        for (int a = 0; a < 2; ++a)
            #pragma unroll
            for (int b = 0; b < 2; ++b) { accm[a][b][0]=0.f; accm[a][b][1]=0.f; accm[a][b][2]=0.f; accm[a][b][3]=0.f; }

        #pragma unroll
        for (int kc = 0; kc < 8; ++kc) {
            bf16x8 af[2], bfr[2];
            #pragma unroll
            for (int it = 0; it < 2; ++it)
                af[it] = *(const bf16x8*)(affwb + (wid * 32 + it * 16 + l15) * CH + kc * 32 + koff);
            #pragma unroll
            for (int rt = 0; rt < 2; ++rt)
                bfr[rt] = *(const bf16x8*)(A_s + swz(rt * 16 + l15, kc * 4 + lgrp));
            #pragma unroll
            for (int it = 0; it < 2; ++it)
                #pragma unroll
                for (int rt = 0; rt < 2; ++rt)
                    accm[it][rt] = __builtin_amdgcn_mfma_f32_16x16x32_bf16(
                        af[it], bfr[rt], accm[it][rt], 0, 0, 0);
        }
        // mod = accm + affb + 1 -> B_s (b64 scatter; C-frag gives 4 consecutive i)
        #pragma unroll
        for (int it = 0; it < 2; ++it) {
            int i0 = wid * 32 + it * 16 + (lgrp << 2);
            f32x4 ab = *(const f32x4*)(affb + i0);
            int chunk = i0 >> 3;
            int sub   = (i0 & 7) << 1;
            #pragma unroll
            for (int rt = 0; rt < 2; ++rt) {
                int row = rt * 16 + l15;
                f32x4 m = accm[it][rt];
                s16x4 o4 = { f2b(m[0] + ab[0] + 1.0f), f2b(m[1] + ab[1] + 1.0f),
                             f2b(m[2] + ab[2] + 1.0f), f2b(m[3] + ab[3] + 1.0f) };
                *(s16x4*)(B_s + swz(row, chunk) + sub) = o4;
            }
        }
        __syncthreads();                                 // BAR2: mod visible, A_s reads done

        // ---- a-prep: a1 = bf16(x*mod) -> A_s ; a2 = bf16(mod^2) -> B_s ----
        #pragma unroll
        for (int k = 0; k < 2; ++k) {
            int row = (k << 4) + urow0;
            bf16x8 mb = *(const bf16x8*)(B_s + swz(row, uch));
            bf16x8 a1v, a2v;
            #pragma unroll
            for (int j = 0; j < 8; ++j) {
                float mf = b2f(mb[j]);
                float xf = (j < 4) ? xld[k][0][j] : xld[k][1][j - 4];
                a1v[j] = f2b(xf * mf);
                a2v[j] = f2b(mf * mf);
            }
            *(bf16x8*)(A_s + swz(row, uch)) = a1v;
            *(bf16x8*)(B_s + swz(row, uch)) = a2v;
        }
        __syncthreads();                                 // BAR3: a1/a2 visible

        // ---- refill xld(t+1) (xld(t) consumed above; lands during ph2+epi+cvt+ph1) ----
        if (t + 1 < NT) {
            const float* xp = x + (r0 + BM) * CH;
            #pragma unroll
            for (int k = 0; k < 2; ++k) {
                int row = (k << 4) + urow0;
                const float* p = xp + row * CH + uch * 8;
                xld[k][0] = *(const f32x4*)p;  xld[k][1] = *(const f32x4*)(p + 4);
            }
        }

        // ---- Phase 2: out0 = a1 @ W^T, ssq = a2 @ (W^2)^T (wave owns 32 o's) ----
        f32x4 acc0[2][2], acc1[2][2];
        #pragma unroll
        for (int a = 0; a < 2; ++a)
            #pragma unroll
            for (int b = 0; b < 2; ++b) {
                acc0[a][b][0]=0.f; acc0[a][b][1]=0.f; acc0[a][b][2]=0.f; acc0[a][b][3]=0.f;
                acc1[a][b][0]=0.f; acc1[a][b][1]=0.f; acc1[a][b][2]=0.f; acc1[a][b][3]=0.f;
            }

        #pragma unroll
        for (int kc = 0; kc < 8; ++kc) {
            bf16x8 bw[2], bw2[2];
            #pragma unroll
            for (int ct = 0; ct < 2; ++ct) {
                int o = wid * 32 + ct * 16 + l15;
                bw [ct] = *(const bf16x8*)(wTb  + o * CH + kc * 32 + koff);
                bw2[ct] = *(const bf16x8*)(wT2b + o * CH + kc * 32 + koff);
            }
            bf16x8 a1f[2], a2f[2];
            #pragma unroll
            for (int rt = 0; rt < 2; ++rt) {
                a1f[rt] = *(const bf16x8*)(A_s + swz(rt * 16 + l15, kc * 4 + lgrp));
                a2f[rt] = *(const bf16x8*)(B_s + swz(rt * 16 + l15, kc * 4 + lgrp));
            }
            #pragma unroll
            for (int rt = 0; rt < 2; ++rt)
                #pragma unroll
                for (int ct = 0; ct < 2; ++ct) {
                    acc0[rt][ct] = __builtin_amdgcn_mfma_f32_16x16x32_bf16(
                        a1f[rt], bw[ct],  acc0[rt][ct], 0, 0, 0);
                    acc1[rt][ct] = __builtin_amdgcn_mfma_f32_16x16x32_bf16(
                        a2f[rt], bw2[ct], acc1[rt][ct], 0, 0, 0);
                }
        }
        __syncthreads();                                 // BAR4: A/B reads done (st overlays)

        // ---- Epilogue: demod + bias -> st (f32 [32][256] over dead A_s+B_s) ----
        #pragma unroll
        for (int ct = 0; ct < 2; ++ct) {
            int o = wid * 32 + ct * 16 + l15;
            float bsv = bias[o];
            #pragma unroll
            for (int rt = 0; rt < 2; ++rt)
                #pragma unroll
                for (int j = 0; j < 4; ++j) {
                    int row = rt * 16 + (lgrp << 2) + j;
                    st[row * 256 + o] = acc0[rt][ct][j] * rsqrtf(acc1[rt][ct][j] + EPS) + bsv;
                }
        }
        __syncthreads();                                 // BAR5: stage visible

        // ---- coalesced stores: 1KB per wave-instruction, 4 iters ----
        #pragma unroll
        for (int k = 0; k < 4; ++k) {
            int u = (k << 9) + tid;
            int row = u >> 6, c4 = u & 63;
            f32x4 v = *(const f32x4*)(st + row * 256 + c4 * 4);
            *(f32x4*)(out + (r0 + row) * CH + c4 * 4) = v;
        }
    }
}

extern "C" void kernel_launch(void* const* d_in, const int* in_sizes, int n_in,
                              void* d_out, int out_size, void* d_ws, size_t ws_size,
                              hipStream_t stream) {
    const float* x      = (const float*)d_in[0];
    const float* style  = (const float*)d_in[1];
    const float* weight = (const float*)d_in[2];
    const float* bias   = (const float*)d_in[3];
    const float* affw   = (const float*)d_in[4];
    const float* affb   = (const float*)d_in[5];
    float* outp = (float*)d_out;

    short* ws    = (short*)d_ws;
    short* wTb   = ws;                 // [256][256] bf16
    short* wT2b  = ws + CH * CH;
    short* affwb = ws + 2 * CH * CH;

    prep_kernel<<<dim3(CH), dim3(CH), 0, stream>>>(weight, affw, wTb, wT2b, affwb);

    // 262144 rows = 512 blocks x NT(16) x BM(32)
    smod_main<<<dim3(512), dim3(512), 0, stream>>>(
        x, style, bias, affb, wTb, wT2b, affwb, outp);
}

// Round 10
// 390.962 us; speedup vs baseline: 1.9134x; 1.9134x over previous
//
#include <hip/hip_runtime.h>

// SpatialStyleModLayer fused kernel, round 10 (MI355X / gfx950)
//   mod  = style @ affine_w^T + affine_b + 1
//   out0 = (x * mod) @ W ;  ssq = (mod^2) @ (W^2) ;  out = out0*rsqrt(ssq+eps)+bias
// R10 = R4 geometry (BM=64, 512thr, 2 blocks/CU, single-shot, no cross-tile
// register prefetch -- R5/R9 proved that spills) + intra-phase L2 pipelining:
//   - phase 2 split into two ROW-half passes: acc 64->32 AGPR, freeing ~32 regs
//   - manual double-buffer of W/affw L2 loads (named stages, parity ternaries
//     folded at compile time by full unroll) -> kc+1 loads in flight during kc MFMAs
//   - per-pass epilogue overlays the dead row-half of A_s/B_s (LDS stays 64KB);
//     pass-0 stores overlap pass-1 MFMAs
// L2 budget: affw 128K + W 2x256K per block = 640KB/64rows -> 2.6GB agg (76us)
// HBM: 533MB (85us). Both under target.

#define CH   256
#define BM   64
#define EPS  1e-8f

typedef __attribute__((ext_vector_type(4))) float f32x4;
typedef __attribute__((ext_vector_type(8))) short bf16x8;
typedef __attribute__((ext_vector_type(4))) short s16x4;

__device__ __forceinline__ short f2b(float f) {          // f32 -> bf16 RNE (HW cvt)
    __bf16 h = (__bf16)f;
    return __builtin_bit_cast(short, h);
}
__device__ __forceinline__ float b2f(short b) {
    union { unsigned u; float f; } v;
    v.u = ((unsigned)(unsigned short)b) << 16;
    return v.f;
}
// Swizzled byte offset into a 64-row x 512B-row bf16 tile. chunk = 16B unit (0..31).
__device__ __forceinline__ int swz(int row, int chunk) {
    return row * 512 + ((chunk ^ (row & 7)) << 4);
}

// One-time weight prep: wTb[o][i]=bf16(W[i][o]); wT2b[o][i]=bf16(bf16(W)^2);
// affwb[i][s]=bf16(affw[i][s]).
__global__ void prep_kernel(const float* __restrict__ weight,
                            const float* __restrict__ affw,
                            short* __restrict__ wTb, short* __restrict__ wT2b,
                            short* __restrict__ affwb)
{
    int t = threadIdx.x, b = blockIdx.x;
    float w  = weight[t * CH + b];
    short wb = f2b(w);
    float wf = b2f(wb);
    wTb  [b * CH + t] = wb;
    wT2b [b * CH + t] = f2b(wf * wf);
    affwb[b * CH + t] = f2b(affw[b * CH + t]);
}

__global__ __launch_bounds__(512, 4)
void smod_main(const float* __restrict__ x, const float* __restrict__ style,
               const float* __restrict__ bias, const float* __restrict__ affb,
               const short* __restrict__ wTb, const short* __restrict__ wT2b,
               const short* __restrict__ affwb,
               float* __restrict__ out)
{
    __shared__ __align__(16) unsigned char smem[65536];  // 64 KB: A_s 32K | B_s 32K
    char* A_s = (char*)smem;            // style-bf16 -> a1 (64 rows x 512B, swizzled)
    char* B_s = (char*)smem + 32768;    // mod       -> a2

    const int tid  = threadIdx.x;
    const int lane = tid & 63;
    const int wid  = tid >> 6;          // 0..7
    const int l15  = lane & 15;
    const int lgrp = lane >> 4;         // 0..3
    const int koff = lgrp << 3;
    const long r0  = (long)blockIdx.x * BM;

    // epilogue staging address: tile-row r (0..63), col o -> overlays dead A/B half
    auto strow = [&](int r) -> char* {
        return (char*)smem + ((r >> 4) & 1) * 32768 + (r >> 5) * 16384 + (r & 15) * 1024;
    };

    // ---- stage style [64][256] f32 -> bf16 into A_s (swizzled) ----
    #pragma unroll
    for (int k = 0; k < 8; ++k) {
        int u = (k << 9) + tid;
        int row = u >> 6, c4 = u & 63;
        f32x4 v = *(const f32x4*)(style + (r0 + row) * CH + c4 * 4);
        s16x4 o4 = { f2b(v[0]), f2b(v[1]), f2b(v[2]), f2b(v[3]) };
        *(s16x4*)(A_s + swz(row, c4 >> 1) + ((c4 & 1) << 3)) = o4;
    }
    __syncthreads();                                     // BAR 1: style visible

    // ---- Phase 1: mod^T = affwb @ style^T (wave owns 32 i's), affw L2 dbuf ----
    f32x4 accm[2][4];
    #pragma unroll
    for (int a = 0; a < 2; ++a)
        #pragma unroll
        for (int b = 0; b < 4; ++b) { accm[a][b][0]=0.f; accm[a][b][1]=0.f; accm[a][b][2]=0.f; accm[a][b][3]=0.f; }

    bf16x8 af_a[2], af_b[2];
    #pragma unroll
    for (int it = 0; it < 2; ++it)
        af_a[it] = *(const bf16x8*)(affwb + (wid * 32 + it * 16 + l15) * CH + 0 + koff);

    #pragma unroll
    for (int kc = 0; kc < 8; ++kc) {
        if (kc < 7) {                                    // prefetch kc+1 into other stage
            #pragma unroll
            for (int it = 0; it < 2; ++it) {
                bf16x8 v = *(const bf16x8*)(affwb + (wid * 32 + it * 16 + l15) * CH + (kc + 1) * 32 + koff);
                if (kc & 1) af_a[it] = v; else af_b[it] = v;
            }
        }
        #pragma unroll
        for (int rt = 0; rt < 4; ++rt) {
            bf16x8 bfr = *(const bf16x8*)(A_s + swz(rt * 16 + l15, kc * 4 + lgrp));
            #pragma unroll
            for (int it = 0; it < 2; ++it)
                accm[it][rt] = __builtin_amdgcn_mfma_f32_16x16x32_bf16(
                    (kc & 1) ? af_b[it] : af_a[it], bfr, accm[it][rt], 0, 0, 0);
        }
    }

    // ---- issue x loads (consumed in a-prep after BAR2; R4-proven placement) ----
    f32x4 xld[8];
    #pragma unroll
    for (int k = 0; k < 8; ++k) {
        int u = (k << 9) + tid;
        int row = u >> 6, q = u & 63;                    // q = 4-elem unit
        xld[k] = *(const f32x4*)(x + (r0 + row) * CH + q * 4);
    }

    // mod = accm + affb + 1 -> B_s (b64 scatter; C-frag gives 4 consecutive i)
    #pragma unroll
    for (int it = 0; it < 2; ++it) {
        int i0 = wid * 32 + it * 16 + (lgrp << 2);
        f32x4 ab = *(const f32x4*)(affb + i0);
        int chunk = i0 >> 3;
        int sub   = (i0 & 7) << 1;
        #pragma unroll
        for (int rt = 0; rt < 4; ++rt) {
            int row = rt * 16 + l15;
            f32x4 m = accm[it][rt];
            s16x4 o4 = { f2b(m[0] + ab[0] + 1.0f), f2b(m[1] + ab[1] + 1.0f),
                         f2b(m[2] + ab[2] + 1.0f), f2b(m[3] + ab[3] + 1.0f) };
            *(s16x4*)(B_s + swz(row, chunk) + sub) = o4;
        }
    }
    __syncthreads();                                     // BAR 2: mod visible, style dead

    // ---- a-prep: a1 = bf16(x*mod) -> A_s ; a2 = bf16(mod^2) -> B_s ----
    #pragma unroll
    for (int k = 0; k < 8; ++k) {
        int u = (k << 9) + tid;
        int row = u >> 6, q = u & 63;
        int boff = swz(row, q >> 1) + ((q & 1) << 3);    // 4-elem (8B) unit
        s16x4 mb = *(const s16x4*)(B_s + boff);
        f32x4 xv = xld[k];
        s16x4 a1v, a2v;
        #pragma unroll
        for (int j = 0; j < 4; ++j) {
            float mf = b2f(mb[j]);
            a1v[j] = f2b(xv[j] * mf);
            a2v[j] = f2b(mf * mf);
        }
        *(s16x4*)(A_s + boff) = a1v;
        *(s16x4*)(B_s + boff) = a2v;
    }
    __syncthreads();                                     // BAR 3: a1/a2 visible

    // ================= Phase 2, pass 0: rows 0..31 =================
    f32x4 acc0[2][2], acc1[2][2];
    bf16x8 bw_a[2], bw2_a[2], bw_b[2], bw2_b[2];
    #pragma unroll
    for (int a = 0; a < 2; ++a)
        #pragma unroll
        for (int b = 0; b < 2; ++b) {
            acc0[a][b][0]=0.f; acc0[a][b][1]=0.f; acc0[a][b][2]=0.f; acc0[a][b][3]=0.f;
            acc1[a][b][0]=0.f; acc1[a][b][1]=0.f; acc1[a][b][2]=0.f; acc1[a][b][3]=0.f;
        }
    #pragma unroll
    for (int ct = 0; ct < 2; ++ct) {
        int o = wid * 32 + ct * 16 + l15;
        bw_a [ct] = *(const bf16x8*)(wTb  + o * CH + koff);
        bw2_a[ct] = *(const bf16x8*)(wT2b + o * CH + koff);
    }
    #pragma unroll
    for (int kc = 0; kc < 8; ++kc) {
        if (kc < 7) {
            #pragma unroll
            for (int ct = 0; ct < 2; ++ct) {
                int o = wid * 32 + ct * 16 + l15;
                bf16x8 v1 = *(const bf16x8*)(wTb  + o * CH + (kc + 1) * 32 + koff);
                bf16x8 v2 = *(const bf16x8*)(wT2b + o * CH + (kc + 1) * 32 + koff);
                if (kc & 1) { bw_a[ct] = v1; bw2_a[ct] = v2; }
                else        { bw_b[ct] = v1; bw2_b[ct] = v2; }
            }
        }
        bf16x8 a1f[2], a2f[2];
        #pragma unroll
        for (int rt = 0; rt < 2; ++rt) {
            a1f[rt] = *(const bf16x8*)(A_s + swz(rt * 16 + l15, kc * 4 + lgrp));
            a2f[rt] = *(const bf16x8*)(B_s + swz(rt * 16 + l15, kc * 4 + lgrp));
        }
        #pragma unroll
        for (int rt = 0; rt < 2; ++rt)
            #pragma unroll
            for (int ct = 0; ct < 2; ++ct) {
                acc0[rt][ct] = __builtin_amdgcn_mfma_f32_16x16x32_bf16(
                    a1f[rt], (kc & 1) ? bw_b[ct]  : bw_a[ct],  acc0[rt][ct], 0, 0, 0);
                acc1[rt][ct] = __builtin_amdgcn_mfma_f32_16x16x32_bf16(
                    a2f[rt], (kc & 1) ? bw2_b[ct] : bw2_a[ct], acc1[rt][ct], 0, 0, 0);
            }
    }
    __syncthreads();                                     // BAR 4: rows 0-31 reads done

    // epilogue 0: demod+bias -> st over dead rows 0..31 of A/B
    #pragma unroll
    for (int ct = 0; ct < 2; ++ct) {
        int o = wid * 32 + ct * 16 + l15;
        float bsv = bias[o];
        #pragma unroll
        for (int rt = 0; rt < 2; ++rt)
            #pragma unroll
            for (int j = 0; j < 4; ++j) {
                int r = rt * 16 + (lgrp << 2) + j;       // 0..31
                *(float*)(strow(r) + o * 4) =
                    acc0[rt][ct][j] * rsqrtf(acc1[rt][ct][j] + EPS) + bsv;
            }
    }
    __syncthreads();                                     // BAR 5: st0 visible

    // stores 0 (overlap pass-1 compute; nothing waits on them)
    #pragma unroll
    for (int k = 0; k < 4; ++k) {
        int u = (k << 9) + tid;
        int row = u >> 6, c4 = u & 63;                   // rows 0..31
        f32x4 v = *(const f32x4*)(strow(row) + c4 * 16);
        *(f32x4*)(out + (r0 + row) * CH + c4 * 4) = v;
    }

    // ================= Phase 2, pass 1: rows 32..63 =================
    #pragma unroll
    for (int a = 0; a < 2; ++a)
        #pragma unroll
        for (int b = 0; b < 2; ++b) {
            acc0[a][b][0]=0.f; acc0[a][b][1]=0.f; acc0[a][b][2]=0.f; acc0[a][b][3]=0.f;
            acc1[a][b][0]=0.f; acc1[a][b][1]=0.f; acc1[a][b][2]=0.f; acc1[a][b][3]=0.f;
        }
    #pragma unroll
    for (int ct = 0; ct < 2; ++ct) {
        int o = wid * 32 + ct * 16 + l15;
        bw_a [ct] = *(const bf16x8*)(wTb  + o * CH + koff);
        bw2_a[ct] = *(const bf16x8*)(wT2b + o * CH + koff);
    }
    #pragma unroll
    for (int kc = 0; kc < 8; ++kc) {
        if (kc < 7) {
            #pragma unroll
            for (int ct = 0; ct < 2; ++ct) {
                int o = wid * 32 + ct * 16 + l15;
                bf16x8 v1 = *(const bf16x8*)(wTb  + o * CH + (kc + 1) * 32 + koff);
                bf16x8 v2 = *(const bf16x8*)(wT2b + o * CH + (kc + 1) * 32 + koff);
                if (kc & 1) { bw_a[ct] = v1; bw2_a[ct] = v2; }
                else        { bw_b[ct] = v1; bw2_b[ct] = v2; }
            }
        }
        bf16x8 a1f[2], a2f[2];
        #pragma unroll
        for (int rt = 0; rt < 2; ++rt) {
            a1f[rt] = *(const bf16x8*)(A_s + swz(32 + rt * 16 + l15, kc * 4 + lgrp));
            a2f[rt] = *(const bf16x8*)(B_s + swz(32 + rt * 16 + l15, kc * 4 + lgrp));
        }
        #pragma unroll
        for (int rt = 0; rt < 2; ++rt)
            #pragma unroll
            for (int ct = 0; ct < 2; ++ct) {
                acc0[rt][ct] = __builtin_amdgcn_mfma_f32_16x16x32_bf16(
                    a1f[rt], (kc & 1) ? bw_b[ct]  : bw_a[ct],  acc0[rt][ct], 0, 0, 0);
                acc1[rt][ct] = __builtin_amdgcn_mfma_f32_16x16x32_bf16(
                    a2f[rt], (kc & 1) ? bw2_b[ct] : bw2_a[ct], acc1[rt][ct], 0, 0, 0);
            }
    }
    __syncthreads();                                     // BAR 6: rows 32-63 reads done

    // epilogue 1: -> st over dead rows 32..63
    #pragma unroll
    for (int ct = 0; ct < 2; ++ct) {
        int o = wid * 32 + ct * 16 + l15;
        float bsv = bias[o];
        #pragma unroll
        for (int rt = 0; rt < 2; ++rt)
            #pragma unroll
            for (int j = 0; j < 4; ++j) {
                int r = 32 + rt * 16 + (lgrp << 2) + j;  // 32..63
                *(float*)(strow(r) + o * 4) =
                    acc0[rt][ct][j] * rsqrtf(acc1[rt][ct][j] + EPS) + bsv;
            }
    }
    __syncthreads();                                     // BAR 7: st1 visible

    // stores 1
    #pragma unroll
    for (int k = 0; k < 4; ++k) {
        int u = (k << 9) + tid;
        int row = 32 + (u >> 6), c4 = u & 63;            // rows 32..63
        f32x4 v = *(const f32x4*)(strow(row) + c4 * 16);
        *(f32x4*)(out + (r0 + row) * CH + c4 * 4) = v;
    }
}

extern "C" void kernel_launch(void* const* d_in, const int* in_sizes, int n_in,
                              void* d_out, int out_size, void* d_ws, size_t ws_size,
                              hipStream_t stream) {
    const float* x      = (const float*)d_in[0];
    const float* style  = (const float*)d_in[1];
    const float* weight = (const float*)d_in[2];
    const float* bias   = (const float*)d_in[3];
    const float* affw   = (const float*)d_in[4];
    const float* affb   = (const float*)d_in[5];
    float* outp = (float*)d_out;

    short* ws    = (short*)d_ws;
    short* wTb   = ws;                 // [256][256] bf16
    short* wT2b  = ws + CH * CH;
    short* affwb = ws + 2 * CH * CH;

    prep_kernel<<<dim3(CH), dim3(CH), 0, stream>>>(weight, affw, wTb, wT2b, affwb);

    const int rows = 4 * 65536;        // 262144
    smod_main<<<dim3(rows / BM), dim3(512), 0, stream>>>(
        x, style, bias, affb, wTb, wT2b, affwb, outp);
}

// Round 11
// 390.009 us; speedup vs baseline: 1.9181x; 1.0024x over previous
//
#include <hip/hip_runtime.h>

// SpatialStyleModLayer fused kernel, round 11 (MI355X / gfx950)
//   mod  = style @ affine_w^T + affine_b + 1
//   out0 = (x * mod) @ W ;  ssq = (mod^2) @ (W^2) ;  out = out0*rsqrt(ssq+eps)+bias
// R11 vs R4 (284us best): identical geometry (BM=64, 512thr, 64KB LDS,
// 2 blocks/CU, 16 waves/CU) but x moves from 32 VGPRs to a DMA'd LDS landing
// buffer, and the a1/a2 tiles are K-halved so everything fits in 64KB:
//   LDS: A_s [64][128]bf16 16K | B_s [64][128]bf16 16K | xland [64][128]f32 32K
//        (style staging [64][256]bf16 32K overlays A_s+B_s; epilogue f32 stage
//         overlays all 64K)
//   phase 2 = two K=128 passes accumulating into the SAME acc (W traffic/block
//   unchanged -- R10's row-split mistake avoided). mod-h1 parks in 8 bf16 regs.
//   x DMA h0 issued at block start (hides under style-stage+ph1); h1 issued
//   after aprep-h0 (hides under ph2-K0). DMA src pre-swizzled (m173) so the
//   aprep read pattern is bank-even.
// Freed VGPRs let the compiler hoist the unrolled affw/W L2 loads (the thing
// VGPR=64+xld made impossible in R4/R10).

#define CH   256
#define BM   64
#define EPS  1e-8f

typedef __attribute__((ext_vector_type(4))) float f32x4;
typedef __attribute__((ext_vector_type(8))) short bf16x8;
typedef __attribute__((ext_vector_type(4))) short s16x4;

__device__ __forceinline__ short f2b(float f) {          // f32 -> bf16 RNE (HW cvt)
    __bf16 h = (__bf16)f;
    return __builtin_bit_cast(short, h);
}
__device__ __forceinline__ float b2f(short b) {
    union { unsigned u; float f; } v;
    v.u = ((unsigned)(unsigned short)b) << 16;
    return v.f;
}
// 512B-row swizzle (style tile): chunk = 16B unit 0..31
__device__ __forceinline__ int swz512(int row, int ch) {
    return row * 512 + ((ch ^ (row & 7)) << 4);
}
// 256B-row swizzle (A_s/B_s half tiles): chunk = 16B unit 0..15
__device__ __forceinline__ int swz256(int row, int ch) {
    return row * 256 + ((ch ^ (row & 7)) << 4);
}
__device__ __forceinline__ void lds_dma16(const float* g, float* l) {
    __builtin_amdgcn_global_load_lds(
        (const __attribute__((address_space(1))) unsigned int*)g,
        (__attribute__((address_space(3))) unsigned int*)l, 16, 0, 0);
}

// One-time weight prep: wTb[o][i]=bf16(W[i][o]); wT2b[o][i]=bf16(bf16(W)^2);
// affwb[i][s]=bf16(affw[i][s]).
__global__ void prep_kernel(const float* __restrict__ weight,
                            const float* __restrict__ affw,
                            short* __restrict__ wTb, short* __restrict__ wT2b,
                            short* __restrict__ affwb)
{
    int t = threadIdx.x, b = blockIdx.x;
    float w  = weight[t * CH + b];
    short wb = f2b(w);
    float wf = b2f(wb);
    wTb  [b * CH + t] = wb;
    wT2b [b * CH + t] = f2b(wf * wf);
    affwb[b * CH + t] = f2b(affw[b * CH + t]);
}

__global__ __launch_bounds__(512, 4)
void smod_main(const float* __restrict__ x, const float* __restrict__ style,
               const float* __restrict__ bias, const float* __restrict__ affb,
               const short* __restrict__ wTb, const short* __restrict__ wT2b,
               const short* __restrict__ affwb,
               float* __restrict__ out)
{
    __shared__ __align__(16) unsigned char smem[65536];  // 64 KB
    char*  sty   = (char*)smem;                // [64][256] bf16 swz512 (phase 1 only)
    char*  A_s   = (char*)smem;                // [64][128] bf16 swz256 (a1 half)
    char*  B_s   = (char*)smem + 16384;        // [64][128] bf16 swz256 (mod -> a2 half)
    float* xland = (float*)(smem + 32768);     // [64][128] f32 (DMA, src-preswizzled)
    float* st    = (float*)smem;               // [64][256] f32 epilogue stage

    const int tid  = threadIdx.x;
    const int lane = tid & 63;
    const int wid  = tid >> 6;                 // 0..7
    const int l15  = lane & 15;
    const int lgrp = lane >> 4;                // 0..3
    const int koff = lgrp << 3;
    const long r0  = (long)blockIdx.x * BM;

    // ---- x DMA issue helper: half h cols [h*128, h*128+128) ----
    // dest: wave-uniform base + lane*16 (linear rows of 512B);
    // src col pre-swizzled so phys 32B-unit u holds cols ((u^(row&7))*8 ..+7).
    auto dma_x_half = [&](int h) {
        #pragma unroll
        for (int k = 0; k < 4; ++k) {
            int j   = wid * 4 + k;                        // row pair 2j,2j+1
            int row = 2 * j + (lane >> 5);
            int c   = lane & 31;                          // dest 16B chunk in row
            int scol = ((((c >> 1) ^ (row & 7)) << 3) | ((c & 1) << 2));
            lds_dma16(x + (r0 + row) * CH + h * 128 + scol, xland + j * 256);
        }
    };

    dma_x_half(0);                                       // lands during stage+ph1

    // ---- stage style [64][256] f32 -> bf16 into sty (swz512) ----
    #pragma unroll
    for (int k = 0; k < 8; ++k) {
        int u = (k << 9) + tid;
        int row = u >> 6, c4 = u & 63;
        f32x4 v = *(const f32x4*)(style + (r0 + row) * CH + c4 * 4);
        s16x4 o4 = { f2b(v[0]), f2b(v[1]), f2b(v[2]), f2b(v[3]) };
        *(s16x4*)(sty + swz512(row, c4 >> 1) + ((c4 & 1) << 3)) = o4;
    }
    __syncthreads();                                     // BAR1: style visible

    // ---- Phase 1: full mod. it=0 -> i in [wid*16,+16); it=1 -> i in [128+wid*16,+16)
    f32x4 accm[2][4];
    #pragma unroll
    for (int a = 0; a < 2; ++a)
        #pragma unroll
        for (int b = 0; b < 4; ++b) { accm[a][b][0]=0.f; accm[a][b][1]=0.f; accm[a][b][2]=0.f; accm[a][b][3]=0.f; }

    #pragma unroll
    for (int kc = 0; kc < 8; ++kc) {
        bf16x8 af[2], bfr[4];
        af[0] = *(const bf16x8*)(affwb + (wid * 16 + l15) * CH + kc * 32 + koff);
        af[1] = *(const bf16x8*)(affwb + (128 + wid * 16 + l15) * CH + kc * 32 + koff);
        #pragma unroll
        for (int rt = 0; rt < 4; ++rt)
            bfr[rt] = *(const bf16x8*)(sty + swz512(rt * 16 + l15, kc * 4 + lgrp));
        __builtin_amdgcn_s_setprio(1);
        #pragma unroll
        for (int it = 0; it < 2; ++it)
            #pragma unroll
            for (int rt = 0; rt < 4; ++rt)
                accm[it][rt] = __builtin_amdgcn_mfma_f32_16x16x32_bf16(
                    af[it], bfr[rt], accm[it][rt], 0, 0, 0);
        __builtin_amdgcn_s_setprio(0);
    }

    // finalize mod: +affb+1; park h1 as bf16 (8 VGPR), frees accm[1]
    const int i_lo = wid * 16 + (lgrp << 2);             // i_local for both halves
    f32x4 ab0 = *(const f32x4*)(affb + i_lo);
    f32x4 ab1 = *(const f32x4*)(affb + 128 + i_lo);
    s16x4 modreg[4];
    #pragma unroll
    for (int rt = 0; rt < 4; ++rt) {
        f32x4 m = accm[1][rt];
        modreg[rt] = s16x4{ f2b(m[0] + ab1[0] + 1.0f), f2b(m[1] + ab1[1] + 1.0f),
                            f2b(m[2] + ab1[2] + 1.0f), f2b(m[3] + ab1[3] + 1.0f) };
    }
    __syncthreads();                                     // BAR2: sty reads done

    // scatter geometry for mod writes (4 consecutive i per lane-group)
    const int mchunk = i_lo >> 3;                        // 16B chunk 0..15
    const int msub   = (i_lo & 7) << 1;                  // byte 0 or 8

    // ---- modwrite-h0: accm[0]+ab0+1 -> B_s ----
    #pragma unroll
    for (int rt = 0; rt < 4; ++rt) {
        int row = rt * 16 + l15;
        f32x4 m = accm[0][rt];
        s16x4 o4 = { f2b(m[0] + ab0[0] + 1.0f), f2b(m[1] + ab0[1] + 1.0f),
                     f2b(m[2] + ab0[2] + 1.0f), f2b(m[3] + ab0[3] + 1.0f) };
        *(s16x4*)(B_s + swz256(row, mchunk) + msub) = o4;
    }
    asm volatile("s_waitcnt vmcnt(0)" ::: "memory");     // x-h0 landed
    __syncthreads();                                     // BAR3: mod-h0 + x-h0 visible

    // ---- aprep-h0: a1 = bf16(x*mod) -> A_s ; a2 = bf16(mod^2) -> B_s (in place)
    // unit = 4 elems; lane-consecutive 16B x-reads are bank-even via src preswizzle
    #pragma unroll
    for (int k = 0; k < 4; ++k) {
        int u = (k << 9) + tid;                          // 2048 units
        int row = u >> 5, c4 = u & 31;
        int boff = swz256(row, c4 >> 1) + ((c4 & 1) << 3);
        s16x4 mb = *(const s16x4*)(B_s + boff);
        f32x4 xv = *(const f32x4*)((char*)xland + row * 512 +
                                   (((c4 >> 1) ^ (row & 7)) << 5) + ((c4 & 1) << 4));
        s16x4 a1v, a2v;
        #pragma unroll
        for (int j = 0; j < 4; ++j) {
            float mf = b2f(mb[j]);
            a1v[j] = f2b(xv[j] * mf);
            a2v[j] = f2b(mf * mf);
        }
        *(s16x4*)(A_s + boff) = a1v;
        *(s16x4*)(B_s + boff) = a2v;
    }
    __syncthreads();                                     // BAR4: a-h0 ready, xland free

    dma_x_half(1);                                       // lands during ph2-K0

    // ---- Phase 2 accumulators (persist across both K-halves) ----
    f32x4 acc0[4][2], acc1[4][2];
    #pragma unroll
    for (int a = 0; a < 4; ++a)
        #pragma unroll
        for (int b = 0; b < 2; ++b) {
            acc0[a][b][0]=0.f; acc0[a][b][1]=0.f; acc0[a][b][2]=0.f; acc0[a][b][3]=0.f;
            acc1[a][b][0]=0.f; acc1[a][b][1]=0.f; acc1[a][b][2]=0.f; acc1[a][b][3]=0.f;
        }

    // ---- ph2-K0: K = 0..127 ----
    #pragma unroll
    for (int kc = 0; kc < 4; ++kc) {
        bf16x8 bw[2], bw2[2];
        #pragma unroll
        for (int ct = 0; ct < 2; ++ct) {
            int o = wid * 32 + ct * 16 + l15;
            bw [ct] = *(const bf16x8*)(wTb  + o * CH + kc * 32 + koff);
            bw2[ct] = *(const bf16x8*)(wT2b + o * CH + kc * 32 + koff);
        }
        bf16x8 a1f[4], a2f[4];
        #pragma unroll
        for (int rt = 0; rt < 4; ++rt) {
            a1f[rt] = *(const bf16x8*)(A_s + swz256(rt * 16 + l15, kc * 4 + lgrp));
            a2f[rt] = *(const bf16x8*)(B_s + swz256(rt * 16 + l15, kc * 4 + lgrp));
        }
        __builtin_amdgcn_s_setprio(1);
        #pragma unroll
        for (int rt = 0; rt < 4; ++rt)
            #pragma unroll
            for (int ct = 0; ct < 2; ++ct) {
                acc0[rt][ct] = __builtin_amdgcn_mfma_f32_16x16x32_bf16(
                    a1f[rt], bw[ct],  acc0[rt][ct], 0, 0, 0);
                acc1[rt][ct] = __builtin_amdgcn_mfma_f32_16x16x32_bf16(
                    a2f[rt], bw2[ct], acc1[rt][ct], 0, 0, 0);
            }
        __builtin_amdgcn_s_setprio(0);
    }
    __syncthreads();                                     // BAR5: a-h0 reads done

    // ---- modwrite-h1: parked modreg -> B_s ----
    #pragma unroll
    for (int rt = 0; rt < 4; ++rt)
        *(s16x4*)(B_s + swz256(rt * 16 + l15, mchunk) + msub) = modreg[rt];
    asm volatile("s_waitcnt vmcnt(0)" ::: "memory");     // x-h1 landed (hid under ph2-K0)
    __syncthreads();                                     // BAR6: mod-h1 + x-h1 visible

    // ---- aprep-h1 ----
    #pragma unroll
    for (int k = 0; k < 4; ++k) {
        int u = (k << 9) + tid;
        int row = u >> 5, c4 = u & 31;
        int boff = swz256(row, c4 >> 1) + ((c4 & 1) << 3);
        s16x4 mb = *(const s16x4*)(B_s + boff);
        f32x4 xv = *(const f32x4*)((char*)xland + row * 512 +
                                   (((c4 >> 1) ^ (row & 7)) << 5) + ((c4 & 1) << 4));
        s16x4 a1v, a2v;
        #pragma unroll
        for (int j = 0; j < 4; ++j) {
            float mf = b2f(mb[j]);
            a1v[j] = f2b(xv[j] * mf);
            a2v[j] = f2b(mf * mf);
        }
        *(s16x4*)(A_s + boff) = a1v;
        *(s16x4*)(B_s + boff) = a2v;
    }
    __syncthreads();                                     // BAR7: a-h1 ready

    // ---- ph2-K1: K = 128..255 ----
    #pragma unroll
    for (int kc = 0; kc < 4; ++kc) {
        bf16x8 bw[2], bw2[2];
        #pragma unroll
        for (int ct = 0; ct < 2; ++ct) {
            int o = wid * 32 + ct * 16 + l15;
            bw [ct] = *(const bf16x8*)(wTb  + o * CH + 128 + kc * 32 + koff);
            bw2[ct] = *(const bf16x8*)(wT2b + o * CH + 128 + kc * 32 + koff);
        }
        bf16x8 a1f[4], a2f[4];
        #pragma unroll
        for (int rt = 0; rt < 4; ++rt) {
            a1f[rt] = *(const bf16x8*)(A_s + swz256(rt * 16 + l15, kc * 4 + lgrp));
            a2f[rt] = *(const bf16x8*)(B_s + swz256(rt * 16 + l15, kc * 4 + lgrp));
        }
        __builtin_amdgcn_s_setprio(1);
        #pragma unroll
        for (int rt = 0; rt < 4; ++rt)
            #pragma unroll
            for (int ct = 0; ct < 2; ++ct) {
                acc0[rt][ct] = __builtin_amdgcn_mfma_f32_16x16x32_bf16(
                    a1f[rt], bw[ct],  acc0[rt][ct], 0, 0, 0);
                acc1[rt][ct] = __builtin_amdgcn_mfma_f32_16x16x32_bf16(
                    a2f[rt], bw2[ct], acc1[rt][ct], 0, 0, 0);
            }
        __builtin_amdgcn_s_setprio(0);
    }
    __syncthreads();                                     // BAR8: all LDS reads done

    // ---- Epilogue: demod + bias -> st (f32 [64][256] over whole smem) ----
    #pragma unroll
    for (int ct = 0; ct < 2; ++ct) {
        int o = wid * 32 + ct * 16 + l15;
        float bsv = bias[o];
        #pragma unroll
        for (int rt = 0; rt < 4; ++rt)
            #pragma unroll
            for (int j = 0; j < 4; ++j) {
                int row = rt * 16 + (lgrp << 2) + j;
                st[row * 256 + o] = acc0[rt][ct][j] * rsqrtf(acc1[rt][ct][j] + EPS) + bsv;
            }
    }
    __syncthreads();                                     // BAR9: stage visible

    // ---- coalesced stores: 1KB per wave-instruction ----
    #pragma unroll
    for (int k = 0; k < 8; ++k) {
        int u = (k << 9) + tid;
        int row = u >> 6, c4 = u & 63;
        f32x4 v = *(const f32x4*)(st + row * 256 + c4 * 4);
        *(f32x4*)(out + (r0 + row) * CH + c4 * 4) = v;
    }
}

extern "C" void kernel_launch(void* const* d_in, const int* in_sizes, int n_in,
                              void* d_out, int out_size, void* d_ws, size_t ws_size,
                              hipStream_t stream) {
    const float* x      = (const float*)d_in[0];
    const float* style  = (const float*)d_in[1];
    const float* weight = (const float*)d_in[2];
    const float* bias   = (const float*)d_in[3];
    const float* affw   = (const float*)d_in[4];
    const float* affb   = (const float*)d_in[5];
    float* outp = (float*)d_out;

    short* ws    = (short*)d_ws;
    short* wTb   = ws;                 // [256][256] bf16
    short* wT2b  = ws + CH * CH;
    short* affwb = ws + 2 * CH * CH;

    prep_kernel<<<dim3(CH), dim3(CH), 0, stream>>>(weight, affw, wTb, wT2b, affwb);

    const int rows = 4 * 65536;        // 262144
    smod_main<<<dim3(rows / BM), dim3(512), 0, stream>>>(
        x, style, bias, affb, wTb, wT2b, affwb, outp);
}